// Round 9
// baseline (970.534 us; speedup 1.0000x reference)
//
#include <hip/hip_runtime.h>
#include <hip/hip_bf16.h>
#include <stdint.h>

typedef unsigned long long u64;

#define N_NODES 10000
#define D_FEAT  128
#define N_EDGES 8192
#define WPR     160       // padded u64 words per packed row (157 valid, pad to 160)
#define WORDS_VALID 157

__device__ __forceinline__ float wave_reduce(float v) {
  #pragma unroll
  for (int o = 32; o > 0; o >>= 1) v += __shfl_xor(v, o, 64);
  return v;
}

// Detect tar_ei element layout per-wave: if the buffer holds int64 (little-endian),
// every odd int32 word is a zero high-word. For genuine int32 indices the odds of
// 64 consecutive odd positions all being 0 are ~0. Returns 2 for int64, 1 for int32.
__device__ __forceinline__ int tar_stride(const int* tar, int lane) {
  int v = tar[2 * lane + 1];
  return (__ballot(v != 0) == 0ull) ? 2 : 1;
}

// K1: per-node projected features yk[n] = x[n,:] . W[(k+1)*128 : (k+2)*128], and zero flags.
__global__ void k_ynode(const float* __restrict__ x, const float* __restrict__ W,
                        float* __restrict__ yn, int* __restrict__ flags) {
  int wid  = (blockIdx.x * blockDim.x + threadIdx.x) >> 6;
  int lane = threadIdx.x & 63;
  if (wid >= N_NODES) return;
  const float* xr = x + (size_t)wid * D_FEAT;
  float x0 = xr[lane], x1 = xr[lane + 64];
  float a0 = x0 * W[128 + lane] + x1 * W[192 + lane];
  float a1 = x0 * W[256 + lane] + x1 * W[320 + lane];
  float a2 = x0 * W[384 + lane] + x1 * W[448 + lane];
  a0 = wave_reduce(a0); a1 = wave_reduce(a1); a2 = wave_reduce(a2);
  if (lane == 0) {
    yn[wid]               = a0;
    yn[N_NODES + wid]     = a1;
    yn[2 * N_NODES + wid] = a2;
    flags[wid] = 0;
  }
}

// K2: mark rows that appear as an edge endpoint (benign write races, all write 1).
__global__ void k_setflags(const int* __restrict__ tar, int* __restrict__ flags) {
  int t    = blockIdx.x * blockDim.x + threadIdx.x;
  int lane = threadIdx.x & 63;
  int stride = tar_stride(tar, lane);
  if (t < 2 * N_EDGES) flags[tar[(size_t)t * stride]] = 1;
}

// K3: bitpack flagged rows of the three adjacency matrices. One wave per (matrix,row).
// Each lane reads 8 consecutive floats (2x float4), forms a byte; 8 shuffles assemble
// 8 u64 words per 512-float chunk; lanes 0..7 store them.
__global__ void k_bitpack(const float* __restrict__ a0m, const float* __restrict__ a1m,
                          const float* __restrict__ a2m, const int* __restrict__ flags,
                          u64* __restrict__ p0, u64* __restrict__ p1, u64* __restrict__ p2) {
  int wg   = (blockIdx.x * blockDim.x + threadIdx.x) >> 6;
  int lane = threadIdx.x & 63;
  if (wg >= 3 * N_NODES) return;
  int mat = wg / N_NODES;
  int row = wg - mat * N_NODES;
  if (!flags[row]) return;
  const float* src = (mat == 0 ? a0m : mat == 1 ? a1m : a2m) + (size_t)row * N_NODES;
  u64* dst = (mat == 0 ? p0 : mat == 1 ? p1 : p2) + (size_t)row * WPR;

  for (int it = 0; it < 20; ++it) {
    int f0 = it * 512 + 8 * lane;
    unsigned byt = 0;
    if (it < 19) {
      float4 va = *reinterpret_cast<const float4*>(src + f0);
      float4 vb = *reinterpret_cast<const float4*>(src + f0 + 4);
      byt = (unsigned)(va.x != 0.f)       | ((unsigned)(va.y != 0.f) << 1)
          | ((unsigned)(va.z != 0.f) << 2) | ((unsigned)(va.w != 0.f) << 3)
          | ((unsigned)(vb.x != 0.f) << 4) | ((unsigned)(vb.y != 0.f) << 5)
          | ((unsigned)(vb.z != 0.f) << 6) | ((unsigned)(vb.w != 0.f) << 7);
    } else {
      #pragma unroll
      for (int t = 0; t < 8; ++t) {
        int idx = f0 + t;
        float v = (idx < N_NODES) ? src[idx] : 0.f;
        byt |= (unsigned)(v != 0.f) << t;
      }
    }
    u64 word = 0;
    #pragma unroll
    for (int s = 0; s < 8; ++s) {
      int b = __shfl((int)byt, (8 * lane + s) & 63, 64);
      word |= (u64)(b & 0xff) << (8 * s);
    }
    if (lane < 8) dst[it * 8 + lane] = word;
  }
}

// K4: one wave per edge. AND packed rows, gather yk for set bits, add xij.W0 term, reduce.
__global__ void k_edge(const float* __restrict__ x, const int* __restrict__ tar,
                       const u64* __restrict__ p0, const u64* __restrict__ p1,
                       const u64* __restrict__ p2, const float* __restrict__ yn,
                       const float* __restrict__ W, const float* __restrict__ b,
                       float* __restrict__ out) {
  int e    = (blockIdx.x * blockDim.x + threadIdx.x) >> 6;
  int lane = threadIdx.x & 63;
  int stride = tar_stride(tar, lane);
  if (e >= N_EDGES) return;
  int i = tar[(size_t)e * stride];
  int j = tar[(size_t)(N_EDGES + e) * stride];

  const float* xi = x + (size_t)i * D_FEAT;
  const float* xj = x + (size_t)j * D_FEAT;
  float acc = xi[lane] * xj[lane] * W[lane] + xi[lane + 64] * xj[lane + 64] * W[lane + 64];

  const u64* r0i = p0 + (size_t)i * WPR; const u64* r0j = p0 + (size_t)j * WPR;
  const u64* r1i = p1 + (size_t)i * WPR; const u64* r1j = p1 + (size_t)j * WPR;
  const u64* r2i = p2 + (size_t)i * WPR; const u64* r2j = p2 + (size_t)j * WPR;
  const float* y0 = yn;
  const float* y1 = yn + N_NODES;
  const float* y2 = yn + 2 * N_NODES;

  for (int w = lane; w < WORDS_VALID; w += 64) {
    u64 m01  = r0i[w] & r0j[w];   // cn_0_1
    u64 m1   = r1i[w] & r1j[w];   // cn_1
    u64 m012 = r2i[w] & r2j[w];   // cn_0_1_2
    u64 m0 = m01  & ~m1;          // cn_0 = cn_0_1 * (1 - cn_1)
    u64 m2 = m012 & ~m01;         // cn_2 = cn_0_1_2 * (1 - cn_0_1)
    int base = w << 6;
    while (m0) { int n = __builtin_ctzll(m0); acc += y0[base + n]; m0 &= m0 - 1; }
    while (m1) { int n = __builtin_ctzll(m1); acc += y1[base + n]; m1 &= m1 - 1; }
    while (m2) { int n = __builtin_ctzll(m2); acc += y2[base + n]; m2 &= m2 - 1; }
  }
  acc = wave_reduce(acc);
  if (lane == 0) out[e] = acc + b[0];
}

// Fallback (no workspace): wave per edge, stream float adjacency rows directly.
__global__ void k_edge_direct(const float* __restrict__ x, const int* __restrict__ tar,
                              const float* __restrict__ a0m, const float* __restrict__ a1m,
                              const float* __restrict__ a2m, const float* __restrict__ W,
                              const float* __restrict__ b, float* __restrict__ out) {
  int e    = (blockIdx.x * blockDim.x + threadIdx.x) >> 6;
  int lane = threadIdx.x & 63;
  int stride = tar_stride(tar, lane);
  if (e >= N_EDGES) return;
  int i = tar[(size_t)e * stride];
  int j = tar[(size_t)(N_EDGES + e) * stride];
  const float* xi = x + (size_t)i * D_FEAT;
  const float* xj = x + (size_t)j * D_FEAT;
  float acc = xi[lane] * xj[lane] * W[lane] + xi[lane + 64] * xj[lane + 64] * W[lane + 64];
  const float* r0i = a0m + (size_t)i * N_NODES; const float* r0j = a0m + (size_t)j * N_NODES;
  const float* r1i = a1m + (size_t)i * N_NODES; const float* r1j = a1m + (size_t)j * N_NODES;
  const float* r2i = a2m + (size_t)i * N_NODES; const float* r2j = a2m + (size_t)j * N_NODES;
  for (int n = lane; n < N_NODES; n += 64) {
    float c01  = r0i[n] * r0j[n];
    float c1   = r1i[n] * r1j[n];
    float c012 = r2i[n] * r2j[n];
    float c0 = c01  * (1.f - c1);
    float c2 = c012 * (1.f - c01);
    if (c0 != 0.f || c1 != 0.f || c2 != 0.f) {
      const float* xn = x + (size_t)n * D_FEAT;
      float s = 0.f;
      for (int d = 0; d < D_FEAT; ++d)
        s += (c0 * W[128 + d] + c1 * W[256 + d] + c2 * W[384 + d]) * xn[d];
      acc += s;
    }
  }
  acc = wave_reduce(acc);
  if (lane == 0) out[e] = acc + b[0];
}

extern "C" void kernel_launch(void* const* d_in, const int* in_sizes, int n_in,
                              void* d_out, int out_size, void* d_ws, size_t ws_size,
                              hipStream_t stream) {
  const float* x    = (const float*)d_in[0];
  const float* a01  = (const float*)d_in[1];
  const float* a1   = (const float*)d_in[2];
  const float* a012 = (const float*)d_in[3];
  const int*   tar  = (const int*)d_in[4];
  const float* W    = (const float*)d_in[5];
  const float* b    = (const float*)d_in[6];
  float* out = (float*)d_out;

  const size_t packed_words = (size_t)N_NODES * WPR;       // per matrix
  const size_t need = 3 * packed_words * sizeof(u64)
                    + 3 * N_NODES * sizeof(float)
                    + N_NODES * sizeof(int);

  if (ws_size >= need) {
    u64* p0 = (u64*)d_ws;
    u64* p1 = p0 + packed_words;
    u64* p2 = p1 + packed_words;
    float* yn  = (float*)(p2 + packed_words);
    int* flags = (int*)(yn + 3 * N_NODES);

    k_ynode   <<<(N_NODES + 3) / 4, 256, 0, stream>>>(x, W, yn, flags);
    k_setflags<<<(2 * N_EDGES + 255) / 256, 256, 0, stream>>>(tar, flags);
    k_bitpack <<<(3 * N_NODES + 3) / 4, 256, 0, stream>>>(a01, a1, a012, flags, p0, p1, p2);
    k_edge    <<<(N_EDGES + 3) / 4, 256, 0, stream>>>(x, tar, p0, p1, p2, yn, W, b, out);
  } else {
    k_edge_direct<<<(N_EDGES + 3) / 4, 256, 0, stream>>>(x, tar, a01, a1, a012, W, b, out);
  }
}